// Round 12
// baseline (828.444 us; speedup 1.0000x reference)
//
#include <hip/hip_runtime.h>

#define NN 50000
#define NE 1600000
#define D  32
#define NREP 16   // counter/bucket replicas (R12: 16, spreads atomics over 2x lines)
#define RCAP 16   // per-replica capacity: Binomial(~55,1/16) mean 3.4, 7-sigma safe
#define SPLIT 2   // gather splits the 16 replicas into 2 groups of 8
#define EPT 2     // edges per thread in k_edge (with hard 64-VGPR cap this time)

__device__ __forceinline__ float b2f(unsigned short v) {
    return __uint_as_float(((unsigned)v) << 16);
}
__device__ __forceinline__ unsigned short f2b(float f) {   // round-to-nearest-even
    unsigned u = __float_as_uint(f);
    u += 0x7FFFu + ((u >> 16) & 1u);
    return (unsigned short)(u >> 16);
}

// ---------------------------------------------------------------------------
// CSR-lite build.  R11 post-mortem: cost is PER-LINE atomic serialization
// (~1.3ns/op/line; 64 ops/line at NREP=8 -> ~100us).  NREP=16 halves
// per-line load (32 ops/line over 50K lines).
// ---------------------------------------------------------------------------
__global__ __launch_bounds__(256) void k_place(const int* __restrict__ src,
                                               int* __restrict__ counts,
                                               int* __restrict__ eid) {
    int e = blockIdx.x * 256 + threadIdx.x;     // over NE (exact grid, 6250 blocks)
    int rep = blockIdx.x & (NREP - 1);
    int s = src[e];
    int pos = atomicAdd(&counts[rep * NN + s], 1);
    if (pos < RCAP) eid[((size_t)rep * NN + s) * RCAP + pos] = e;  // clamp; never hit
}

// ---------------------------------------------------------------------------
// Segment-sum as gather over the 16 replica buckets.
// Thread (n, c, q): sums float4 q over replicas 8c..8c+7 of node n.
// Bucket base (rep*NN+n)*RCAP*4B = 64B-aligned -> int4 loads legal.
// ---------------------------------------------------------------------------
__global__ __launch_bounds__(256) void k_gather(const float* __restrict__ ew,
                                                const int* __restrict__ counts,
                                                const int* __restrict__ eid,
                                                float* __restrict__ parts) {
    int i = blockIdx.x * 256 + threadIdx.x;     // over NN*SPLIT*8 = 800K (exact grid)
    int q = i & 7;
    int t = i >> 3;
    int c = t & 1;
    int n = t >> 1;
    const int qo = q << 2;

    float4 acc = make_float4(0.f, 0.f, 0.f, 0.f);
#pragma unroll
    for (int rr = 0; rr < NREP / SPLIT; rr++) {
        int rep = c * (NREP / SPLIT) + rr;
        int cnt = counts[rep * NN + n];
        if (cnt > RCAP) cnt = RCAP;
        const int* bucket = eid + ((size_t)rep * NN + n) * RCAP;
        int r = 0;
        for (; r + 4 <= cnt; r += 4) {
            int4 e4 = *reinterpret_cast<const int4*>(bucket + r);
            float4 v0 = *reinterpret_cast<const float4*>(ew + (size_t)e4.x * D + qo);
            float4 v1 = *reinterpret_cast<const float4*>(ew + (size_t)e4.y * D + qo);
            float4 v2 = *reinterpret_cast<const float4*>(ew + (size_t)e4.z * D + qo);
            float4 v3 = *reinterpret_cast<const float4*>(ew + (size_t)e4.w * D + qo);
            acc.x += (v0.x + v1.x) + (v2.x + v3.x);
            acc.y += (v0.y + v1.y) + (v2.y + v3.y);
            acc.z += (v0.z + v1.z) + (v2.z + v3.z);
            acc.w += (v0.w + v1.w) + (v2.w + v3.w);
        }
        for (; r < cnt; ++r) {
            int e0 = bucket[r];
            float4 v0 = *reinterpret_cast<const float4*>(ew + (size_t)e0 * D + qo);
            acc.x += v0.x; acc.y += v0.y; acc.z += v0.z; acc.w += v0.w;
        }
    }
    *reinterpret_cast<float4*>(parts + ((size_t)c * NN + n) * D + qo) = acc;
}

// ---------------------------------------------------------------------------
// node_term (bf16) = x@w_x + (p0+p1)@w_ew_j   (unchanged)
// ---------------------------------------------------------------------------
__global__ __launch_bounds__(256) void k_node(const float* __restrict__ x,
                                              const float* __restrict__ parts,
                                              const float* __restrict__ w_x,
                                              const float* __restrict__ w_ew_j,
                                              unsigned short* __restrict__ node_term) {
    int i = blockIdx.x * 256 + threadIdx.x;     // n*32 + o (exact grid)
    int n = i >> 5, o = i & 31;
    const float* p0 = parts + (size_t)n * D;
    const float* p1 = parts + ((size_t)NN + n) * D;
    float acc = 0.f;
#pragma unroll
    for (int k = 0; k < D; k++) {
        float sw = p0[k] + p1[k];
        acc += x[(size_t)n * D + k] * w_x[k * D + o] + sw * w_ew_j[k * D + o];
    }
    node_term[i] = f2b(acc);
}

// ---------------------------------------------------------------------------
// out[e][4q..] = nt[s][q] + nt[d][q] + sum_k ew[e][k] * w_ew_i[k][4q..]
// EPT=2 with a HARD register cap: __launch_bounds__(256, 8) forces VGPR<=64
// so 8 waves/SIMD stay eligible (R11's EPT=2 hit VGPR=76 / 28% occupancy and
// regressed; the LDS-halving itself is sound: 32->16 ds_read_b128 per edge).
// ---------------------------------------------------------------------------
__global__ __launch_bounds__(256, 8) void k_edge(const float* __restrict__ ew,
                                                 const int* __restrict__ src,
                                                 const int* __restrict__ dst,
                                                 const unsigned short* __restrict__ nt,
                                                 const float* __restrict__ w_ew_i,
                                                 float* __restrict__ out) {
    __shared__ float wsm[D * D];
    {
        int t4 = threadIdx.x * 4;
        *reinterpret_cast<float4*>(wsm + t4) =
            *reinterpret_cast<const float4*>(w_ew_i + t4);
    }
    __syncthreads();

    int i = blockIdx.x * 256 + threadIdx.x;     // over (NE/EPT)*8 = 6.4M (exact grid)
    int q = i & 7;
    int g = i >> 3;                             // 800K edge pairs
    int e0 = g * EPT;
    const int qo = q << 2;

    int2 s2 = *reinterpret_cast<const int2*>(src + e0);
    int2 d2 = *reinterpret_cast<const int2*>(dst + e0);

    ushort4 a0 = *reinterpret_cast<const ushort4*>(nt + (size_t)s2.x * D + qo);
    ushort4 b0 = *reinterpret_cast<const ushort4*>(nt + (size_t)d2.x * D + qo);
    ushort4 a1 = *reinterpret_cast<const ushort4*>(nt + (size_t)s2.y * D + qo);
    ushort4 b1 = *reinterpret_cast<const ushort4*>(nt + (size_t)d2.y * D + qo);

    float4 acc0 = make_float4(b2f(a0.x) + b2f(b0.x), b2f(a0.y) + b2f(b0.y),
                              b2f(a0.z) + b2f(b0.z), b2f(a0.w) + b2f(b0.w));
    float4 acc1 = make_float4(b2f(a1.x) + b2f(b1.x), b2f(a1.y) + b2f(b1.y),
                              b2f(a1.z) + b2f(b1.z), b2f(a1.w) + b2f(b1.w));

    const float4* ewp0 = reinterpret_cast<const float4*>(ew + (size_t)e0 * D);
    const float4* ewp1 = reinterpret_cast<const float4*>(ew + (size_t)(e0 + 1) * D);
#pragma unroll
    for (int kq = 0; kq < 8; kq++) {
        float4 wv0 = *reinterpret_cast<const float4*>(wsm + (kq * 4 + 0) * D + qo);
        float4 wv1 = *reinterpret_cast<const float4*>(wsm + (kq * 4 + 1) * D + qo);
        float4 wv2 = *reinterpret_cast<const float4*>(wsm + (kq * 4 + 2) * D + qo);
        float4 wv3 = *reinterpret_cast<const float4*>(wsm + (kq * 4 + 3) * D + qo);

        float4 u = ewp0[kq];
        acc0.x += u.x * wv0.x + u.y * wv1.x + u.z * wv2.x + u.w * wv3.x;
        acc0.y += u.x * wv0.y + u.y * wv1.y + u.z * wv2.y + u.w * wv3.y;
        acc0.z += u.x * wv0.z + u.y * wv1.z + u.z * wv2.z + u.w * wv3.z;
        acc0.w += u.x * wv0.w + u.y * wv1.w + u.z * wv2.w + u.w * wv3.w;

        float4 v = ewp1[kq];
        acc1.x += v.x * wv0.x + v.y * wv1.x + v.z * wv2.x + v.w * wv3.x;
        acc1.y += v.x * wv0.y + v.y * wv1.y + v.z * wv2.y + v.w * wv3.y;
        acc1.z += v.x * wv0.z + v.y * wv1.z + v.z * wv2.z + v.w * wv3.z;
        acc1.w += v.x * wv0.w + v.y * wv1.w + v.z * wv2.w + v.w * wv3.w;
    }

    *reinterpret_cast<float4*>(out + (size_t)e0 * D + qo) = acc0;
    *reinterpret_cast<float4*>(out + (size_t)(e0 + 1) * D + qo) = acc1;
}

// ---------------------------------------------------------------------------
extern "C" void kernel_launch(void* const* d_in, const int* in_sizes, int n_in,
                              void* d_out, int out_size, void* d_ws, size_t ws_size,
                              hipStream_t stream) {
    const float* x      = (const float*)d_in[0];
    const int*   ei     = (const int*)d_in[1];
    const float* ew     = (const float*)d_in[2];
    const float* w_x    = (const float*)d_in[3];
    const float* w_ew_i = (const float*)d_in[4];
    const float* w_ew_j = (const float*)d_in[5];
    float*       out    = (float*)d_out;

    const int* src = ei;            // edge_index[0]
    const int* dst = ei + NE;       // edge_index[1]

    // workspace layout (~67.2 MB): node_term (bf16, 3.2MB) overlays eid
    // (dead after k_gather)
    float* parts        = (float*)d_ws;                        // [SPLIT][NN][D] 12.8 MB
    int*   counts       = (int*)(parts + (size_t)SPLIT * NN * D); // [NREP][NN]  3.2 MB
    int*   eid          = counts + (size_t)NREP * NN;          // [NREP][NN][RCAP] 51.2 MB
    unsigned short* ntb = (unsigned short*)eid;                // [NN][D] bf16 overlay 3.2 MB

    // zero the replicated counters every call
    hipMemsetAsync(counts, 0, (size_t)NREP * NN * sizeof(int), stream);

    k_place <<<NE / 256,               256, 0, stream>>>(src, counts, eid);
    k_gather<<<NN * SPLIT * 8 / 256,   256, 0, stream>>>(ew, counts, eid, parts);
    k_node  <<<NN * D / 256,           256, 0, stream>>>(x, parts, w_x, w_ew_j, ntb);
    k_edge  <<<(NE / EPT) * 8 / 256,   256, 0, stream>>>(ew, src, dst, ntb, w_ew_i, out);
}

// Round 13
// 237.396 us; speedup vs baseline: 3.4897x; 3.4897x over previous
//
#include <hip/hip_runtime.h>

#define NN 50000
#define NE 1600000
#define D  32
#define NRANGE 256
#define RC  8192      // entries per range region; E[6250], +24 sigma
#define EPB 16384     // edges per pass-1 block
#define SPLIT 2       // gather concurrency split

__device__ __forceinline__ float b2f(unsigned short v) {
    return __uint_as_float(((unsigned)v) << 16);
}
__device__ __forceinline__ unsigned short f2b(float f) {   // round-to-nearest-even
    unsigned u = __float_as_uint(f);
    u += 0x7FFFu + ((u >> 16) & 1u);
    return (unsigned short)(u >> 16);
}

__device__ __forceinline__ int range_of(int s)  { return (int)(((unsigned)s * 256u) / 50000u); }
__device__ __forceinline__ int range_beg(int r) { return (int)(((unsigned)r * 50000u + 255u) >> 8); }

// ---------------------------------------------------------------------------
// Pass 1: partition edges into 256 node-range regions, COALESCED writes.
// R12 post-mortem: k_place's 133us == 89MB of random dirty 64B lines (4B
// scattered stores thrash L2).  Here: LDS histogram -> global chunk reserve
// (256 atomics/block) -> LDS reorder -> sequential full-line writes.
// Entry packing: low 21 bits = edge id (<2^21), bits 21.. = node-local id.
// ---------------------------------------------------------------------------
__global__ __launch_bounds__(1024) void k_part1(const int* __restrict__ src,
                                                int* __restrict__ cursor,
                                                unsigned int* __restrict__ buf) {
    __shared__ unsigned int sbuf[EPB];       // 64 KB
    __shared__ int hist[NRANGE];
    __shared__ int scanb[NRANGE];
    __shared__ int lofs[NRANGE + 1];
    __shared__ int gbase[NRANGE];

    const int t = threadIdx.x;
    const long long e0 = (long long)blockIdx.x * EPB;

    for (int r = t; r < NRANGE; r += 1024) hist[r] = 0;
    __syncthreads();

    int myr[16], myrank[16], mys[16];
#pragma unroll
    for (int k = 0; k < 16; k++) {
        long long e = e0 + t + (long long)k * 1024;
        int r = -1, rk = 0, s = 0;
        if (e < NE) {
            s = src[e];
            r = range_of(s);
            rk = atomicAdd(&hist[r], 1);
        }
        myr[k] = r; myrank[k] = rk; mys[k] = s;
    }
    __syncthreads();

    if (t < NRANGE) {
        gbase[t] = atomicAdd(&cursor[t], hist[t]);
        scanb[t] = hist[t];
    }
    __syncthreads();
    for (int off = 1; off < NRANGE; off <<= 1) {       // Hillis-Steele inclusive
        int v = 0;
        if (t < NRANGE && t >= off) v = scanb[t - off];
        __syncthreads();
        if (t < NRANGE) scanb[t] += v;
        __syncthreads();
    }
    if (t < NRANGE) lofs[t + 1] = scanb[t];
    if (t == 0) lofs[0] = 0;
    __syncthreads();

#pragma unroll
    for (int k = 0; k < 16; k++) {
        if (myr[k] >= 0) {
            int r = myr[k];
            unsigned int pk = (unsigned int)(e0 + t + (long long)k * 1024)
                            | ((unsigned int)(mys[k] - range_beg(r)) << 21);
            sbuf[lofs[r] + myrank[k]] = pk;
        }
    }
    __syncthreads();

    const int total = lofs[NRANGE];
    for (int i = t; i < total; i += 1024) {
        int lo = 0, hi = NRANGE - 1;                   // find r: lofs[r]<=i<lofs[r+1]
        while (lo < hi) { int mid = (lo + hi + 1) >> 1; if (lofs[mid] <= i) lo = mid; else hi = mid - 1; }
        buf[(size_t)lo * RC + gbase[lo] + (i - lofs[lo])] = sbuf[i];
    }
}

// ---------------------------------------------------------------------------
// Pass 2: one block per range; LDS-sort entries by local node id -> exact,
// contiguous CSR (eid) + per-node (off, cnt).  All global IO coalesced.
// ---------------------------------------------------------------------------
__global__ __launch_bounds__(1024) void k_part2(const int* __restrict__ cursor,
                                                const unsigned int* __restrict__ buf,
                                                int* __restrict__ eid,
                                                int* __restrict__ node_off,
                                                int* __restrict__ node_cnt) {
    __shared__ int sout[RC];                 // 32 KB
    __shared__ int hist[NRANGE];
    __shared__ int scanb[NRANGE];
    __shared__ int lofs[NRANGE + 1];
    __shared__ int cur[NRANGE];

    const int r = blockIdx.x;
    const int t = threadIdx.x;
    int cnt = cursor[r];
    if (cnt > RC) cnt = RC;                  // impossible; guards OOB
    const int sbeg = range_beg(r);
    const int nr = range_beg(r + 1) - sbeg;  // nodes in this range (<=196)

    for (int i = t; i < NRANGE; i += 1024) hist[i] = 0;
    __syncthreads();

    unsigned int mypk[8]; int myrk[8];
#pragma unroll
    for (int k = 0; k < 8; k++) {
        int i = t + k * 1024;
        unsigned int pk = 0; int rk = 0;
        if (i < cnt) {
            pk = buf[(size_t)r * RC + i];
            rk = atomicAdd(&hist[pk >> 21], 1);
        }
        mypk[k] = pk; myrk[k] = rk;
    }
    __syncthreads();

    if (t < NRANGE) scanb[t] = hist[t];
    __syncthreads();
    for (int off = 1; off < NRANGE; off <<= 1) {
        int v = 0;
        if (t < NRANGE && t >= off) v = scanb[t - off];
        __syncthreads();
        if (t < NRANGE) scanb[t] += v;
        __syncthreads();
    }
    if (t < NRANGE) lofs[t + 1] = scanb[t];
    if (t == 0) lofs[0] = 0;
    __syncthreads();

#pragma unroll
    for (int k = 0; k < 8; k++) {
        int i = t + k * 1024;
        if (i < cnt) {
            unsigned int pk = mypk[k];
            sout[lofs[pk >> 21] + myrk[k]] = (int)(pk & 0x1FFFFFu);
        }
    }
    __syncthreads();

    for (int i = t; i < cnt; i += 1024) eid[(size_t)r * RC + i] = sout[i];
    if (t < nr) {
        node_off[sbeg + t] = r * RC + lofs[t];
        node_cnt[sbeg + t] = hist[t];
    }
}

// ---------------------------------------------------------------------------
// Segment-sum gather over the exact CSR.  Thread (n,c,q): half c of node n's
// edge list, float4 quad q.  Unroll-4 batches the eid->row chains.
// ---------------------------------------------------------------------------
__global__ __launch_bounds__(256) void k_gather(const float* __restrict__ ew,
                                                const int* __restrict__ node_off,
                                                const int* __restrict__ node_cnt,
                                                const int* __restrict__ eid,
                                                float* __restrict__ parts) {
    int i = blockIdx.x * 256 + threadIdx.x;     // over NN*SPLIT*8 = 800K (exact grid)
    int q = i & 7;
    int t2 = i >> 3;
    int c = t2 & 1;
    int n = t2 >> 1;
    const int qo = q << 2;

    const int beg = node_off[n];
    const int cnt = node_cnt[n];
    const int half = (cnt + 1) >> 1;
    int r0 = c * half;
    int r1 = r0 + half; if (r1 > cnt) r1 = cnt;
    const int* bucket = eid + beg;

    float4 acc = make_float4(0.f, 0.f, 0.f, 0.f);
    int r = r0;
    for (; r + 4 <= r1; r += 4) {
        int ea = bucket[r + 0];
        int eb = bucket[r + 1];
        int ec = bucket[r + 2];
        int ed = bucket[r + 3];
        float4 v0 = *reinterpret_cast<const float4*>(ew + (size_t)ea * D + qo);
        float4 v1 = *reinterpret_cast<const float4*>(ew + (size_t)eb * D + qo);
        float4 v2 = *reinterpret_cast<const float4*>(ew + (size_t)ec * D + qo);
        float4 v3 = *reinterpret_cast<const float4*>(ew + (size_t)ed * D + qo);
        acc.x += (v0.x + v1.x) + (v2.x + v3.x);
        acc.y += (v0.y + v1.y) + (v2.y + v3.y);
        acc.z += (v0.z + v1.z) + (v2.z + v3.z);
        acc.w += (v0.w + v1.w) + (v2.w + v3.w);
    }
    for (; r < r1; ++r) {
        int e0 = bucket[r];
        float4 v0 = *reinterpret_cast<const float4*>(ew + (size_t)e0 * D + qo);
        acc.x += v0.x; acc.y += v0.y; acc.z += v0.z; acc.w += v0.w;
    }
    *reinterpret_cast<float4*>(parts + ((size_t)c * NN + n) * D + qo) = acc;
}

// ---------------------------------------------------------------------------
// node_term (bf16) = x@w_x + (p0+p1)@w_ew_j   (R10 exact)
// ---------------------------------------------------------------------------
__global__ __launch_bounds__(256) void k_node(const float* __restrict__ x,
                                              const float* __restrict__ parts,
                                              const float* __restrict__ w_x,
                                              const float* __restrict__ w_ew_j,
                                              unsigned short* __restrict__ node_term) {
    int i = blockIdx.x * 256 + threadIdx.x;     // n*32 + o (exact grid)
    int n = i >> 5, o = i & 31;
    const float* p0 = parts + (size_t)n * D;
    const float* p1 = parts + ((size_t)NN + n) * D;
    float acc = 0.f;
#pragma unroll
    for (int k = 0; k < D; k++) {
        float sw = p0[k] + p1[k];
        acc += x[(size_t)n * D + k] * w_x[k * D + o] + sw * w_ew_j[k * D + o];
    }
    node_term[i] = f2b(acc);
}

// ---------------------------------------------------------------------------
// out[e][4q..] = nt[s][q] + nt[d][q] + sum_k ew[e][k]*w_ew_i[k][4q..]
// R10 exact (EPT=1, VGPR 32, occ 78%, 130us).  R11/R12 closed the EPT>1
// arc: reg pressure or spills always lose.
// ---------------------------------------------------------------------------
__global__ __launch_bounds__(256) void k_edge(const float* __restrict__ ew,
                                              const int* __restrict__ src,
                                              const int* __restrict__ dst,
                                              const unsigned short* __restrict__ nt,
                                              const float* __restrict__ w_ew_i,
                                              float* __restrict__ out) {
    __shared__ float wsm[D * D];
    {
        int t4 = threadIdx.x * 4;
        *reinterpret_cast<float4*>(wsm + t4) =
            *reinterpret_cast<const float4*>(w_ew_i + t4);
    }
    __syncthreads();

    int i = blockIdx.x * 256 + threadIdx.x;     // over NE*8 = 12.8M (exact grid)
    int e = i >> 3, q = i & 7;
    int s = src[e];
    int d = dst[e];
    const int qo = q << 2;

    ushort4 a4 = *reinterpret_cast<const ushort4*>(nt + (size_t)s * D + qo);
    ushort4 b4 = *reinterpret_cast<const ushort4*>(nt + (size_t)d * D + qo);
    float4 acc = make_float4(b2f(a4.x) + b2f(b4.x),
                             b2f(a4.y) + b2f(b4.y),
                             b2f(a4.z) + b2f(b4.z),
                             b2f(a4.w) + b2f(b4.w));

    const float4* ewp = reinterpret_cast<const float4*>(ew + (size_t)e * D);
#pragma unroll
    for (int kq = 0; kq < 8; kq++) {
        float4 e4 = ewp[kq];
        const float ev[4] = {e4.x, e4.y, e4.z, e4.w};
#pragma unroll
        for (int j = 0; j < 4; j++) {
            const int k = kq * 4 + j;
            float4 wv = *reinterpret_cast<const float4*>(wsm + k * D + qo);
            acc.x += ev[j] * wv.x;
            acc.y += ev[j] * wv.y;
            acc.z += ev[j] * wv.z;
            acc.w += ev[j] * wv.w;
        }
    }

    *reinterpret_cast<float4*>(out + (size_t)e * D + qo) = acc;
}

// ---------------------------------------------------------------------------
extern "C" void kernel_launch(void* const* d_in, const int* in_sizes, int n_in,
                              void* d_out, int out_size, void* d_ws, size_t ws_size,
                              hipStream_t stream) {
    const float* x      = (const float*)d_in[0];
    const int*   ei     = (const int*)d_in[1];
    const float* ew     = (const float*)d_in[2];
    const float* w_x    = (const float*)d_in[3];
    const float* w_ew_i = (const float*)d_in[4];
    const float* w_ew_j = (const float*)d_in[5];
    float*       out    = (float*)d_out;

    const int* src = ei;            // edge_index[0]
    const int* dst = ei + NE;       // edge_index[1]

    // workspace (~29.3 MB).  nt (bf16, 3.2MB) overlays buf (dead after part2).
    float*        parts    = (float*)d_ws;                       // [2][NN][D] 12.8 MB
    int*          node_off = (int*)(parts + (size_t)SPLIT * NN * D); // [NN]   200 KB
    int*          node_cnt = node_off + NN;                      // [NN]       200 KB
    int*          cursor   = node_cnt + NN;                      // [NRANGE]     1 KB
    unsigned int* buf      = (unsigned int*)(cursor + NRANGE);   // [NRANGE][RC] 8 MB
    int*          eid      = (int*)(buf + (size_t)NRANGE * RC);  // [NRANGE][RC] 8 MB
    unsigned short* ntb    = (unsigned short*)buf;               // [NN][D] bf16 overlay

    hipMemsetAsync(cursor, 0, NRANGE * sizeof(int), stream);

    k_part1 <<<(NE + EPB - 1) / EPB,  1024, 0, stream>>>(src, cursor, buf);
    k_part2 <<<NRANGE,                1024, 0, stream>>>(cursor, buf, eid, node_off, node_cnt);
    k_gather<<<NN * SPLIT * 8 / 256,  256,  0, stream>>>(ew, node_off, node_cnt, eid, parts);
    k_node  <<<NN * D / 256,          256,  0, stream>>>(x, parts, w_x, w_ew_j, ntb);
    k_edge  <<<NE * 8 / 256,          256,  0, stream>>>(ew, src, dst, ntb, w_ew_i, out);
}